// Round 3
// baseline (399.952 us; speedup 1.0000x reference)
//
#include <hip/hip_runtime.h>

// RNNT joint: out = log_softmax( tanh(enc@W_e + dec@W_d + b1) @ W2 )
// B=4, T=256, U=128, D=512, NCLS=1024.
// ws layout: ep (B*T x D fp32, 2MB) | dp (B*U x D fp32, 1MB) | W2 packed bf16 (1MB)

#define BB 4
#define TT 256
#define UU 128
#define DD 512
#define CC 1024

using f32x16 = __attribute__((ext_vector_type(16))) float;
using bf16x8 = __attribute__((ext_vector_type(8))) __bf16;

static __device__ __forceinline__ unsigned short f2bf(float f) {
    unsigned int u = __float_as_uint(f);
    unsigned int r = (u + 0x7FFFu + ((u >> 16) & 1u)) >> 16;
    return (unsigned short)r;
}

// tanh(x) = 1 - 2/(exp2(2*log2e*x)+1); v_exp + v_rcp, no IEEE divide sequence
static __device__ __forceinline__ float tanh_fast(float x) {
    float a = x * 2.8853900817779268f;           // 2*log2(e)
    a = fminf(30.f, fmaxf(-30.f, a));
    float e = __expf(a * 0.6931471805599453f);   // folds to v_exp(a) since __expf(y)=exp2(y*log2e)
    float r = __builtin_amdgcn_rcpf(e + 1.0f);
    return __builtin_fmaf(-2.f, r, 1.f);
}

// ---- prep: fused enc/dec projection. C[m][n] = A[m][:] @ W[:][n] (+bias) ----
__global__ __launch_bounds__(256) void proj_fused(
    const float* __restrict__ enc, const float* __restrict__ dec,
    const float* __restrict__ W_e, const float* __restrict__ W_d,
    const float* __restrict__ b1,
    float* __restrict__ ep, float* __restrict__ dp)
{
    __shared__ float As[32][34];
    __shared__ float Ws[32][68];
    const int mb = blockIdx.x * 32;
    const int n0 = blockIdx.y * 64;
    const bool is_enc = (mb < BB * TT);
    const float* A = is_enc ? enc + (size_t)mb * DD
                            : dec + (size_t)(mb - BB * TT) * DD;
    const float* W = is_enc ? W_e : W_d;
    float* C = is_enc ? ep + (size_t)mb * DD
                      : dp + (size_t)(mb - BB * TT) * DD;
    const int tid = threadIdx.x;
    const int tx = tid & 15, ty = tid >> 4;
    float acc[2][4] = {};
    for (int k0 = 0; k0 < DD; k0 += 32) {
        __syncthreads();
        {
            const int row = tid >> 3, kk = (tid & 7) * 4;
            float4 v = *reinterpret_cast<const float4*>(A + (size_t)row * DD + k0 + kk);
            As[kk][row] = v.x; As[kk + 1][row] = v.y;
            As[kk + 2][row] = v.z; As[kk + 3][row] = v.w;
            const int wk = tid >> 3, wc2 = (tid & 7) * 8;
            float4 w0 = *reinterpret_cast<const float4*>(W + (size_t)(k0 + wk) * DD + n0 + wc2);
            float4 w1 = *reinterpret_cast<const float4*>(W + (size_t)(k0 + wk) * DD + n0 + wc2 + 4);
            *reinterpret_cast<float4*>(&Ws[wk][wc2]) = w0;
            *reinterpret_cast<float4*>(&Ws[wk][wc2 + 4]) = w1;
        }
        __syncthreads();
        #pragma unroll 4
        for (int kk = 0; kk < 32; ++kk) {
            float a0 = As[kk][ty * 2], a1 = As[kk][ty * 2 + 1];
            float w0 = Ws[kk][tx * 4], w1 = Ws[kk][tx * 4 + 1];
            float w2 = Ws[kk][tx * 4 + 2], w3 = Ws[kk][tx * 4 + 3];
            acc[0][0] += a0 * w0; acc[0][1] += a0 * w1;
            acc[0][2] += a0 * w2; acc[0][3] += a0 * w3;
            acc[1][0] += a1 * w0; acc[1][1] += a1 * w1;
            acc[1][2] += a1 * w2; acc[1][3] += a1 * w3;
        }
    }
    float bb[4] = {0.f, 0.f, 0.f, 0.f};
    if (is_enc) {
        #pragma unroll
        for (int j = 0; j < 4; ++j) bb[j] = b1[n0 + tx * 4 + j];
    }
    #pragma unroll
    for (int i = 0; i < 2; ++i) {
        float4 v;
        v.x = acc[i][0] + bb[0]; v.y = acc[i][1] + bb[1];
        v.z = acc[i][2] + bb[2]; v.w = acc[i][3] + bb[3];
        *reinterpret_cast<float4*>(C + (size_t)(ty * 2 + i) * DD + n0 + tx * 4) = v;
    }
}

// ---- prep: pack W2 (512x1024 f32) -> bf16 fragment layout: ((k>>3)*1024+c)*8+(k&7) ----
__global__ __launch_bounds__(256) void pack_w2(
    const float* __restrict__ W2, unsigned short* __restrict__ w2p)
{
    int i = blockIdx.x * 256 + threadIdx.x;
    int k = i >> 10, c = i & 1023;
    int idx = (((k >> 3) * CC) + c) * 8 + (k & 7);
    w2p[idx] = f2bf(W2[i]);
}

// ---- fused joint kernel, SWAPPED-OPERAND orientation ----
// grid = B*T*2, block = 1024 thr = 16 waves (2 u-halves x 8 col-slices).
// wave-tile = 32 u-rows x 128 cols. acc = mfma(W2frag, hidfrag): D col = lane
// = u-row -> row stats are lane-local (63 fmax + 1 shfl), no butterflies.
// Output transposed back through per-wave LDS slots before coalesced stores.
__global__ __launch_bounds__(1024, 4) void joint_kernel(
    const float* __restrict__ ep, const float* __restrict__ dp,
    const unsigned short* __restrict__ w2p, float* __restrict__ out)
{
    __shared__ __align__(16) unsigned char ldsA[64 * 1024]; // hidden, later transpose scratch
    __shared__ float maxw[64][9];
    __shared__ float sumw[64][9];

    const int bid = blockIdx.x;
    const int bt  = bid >> 1;
    const int u0  = (bid & 1) * 64;
    const int b   = bt >> 8;
    const int tid = threadIdx.x;

    // phase 1: hidden[row][k] = tanh(ep[bt][k] + dp[row][k]) -> LDS bf16
    // layout: frag (ktag,row) at ktag*1024 + rsw*16, rsw = ((row^ktag)&31)|(row&32)
    {
        const int row = tid >> 4;                 // 0..63
        const int kq  = tid & 15;
        const float* eprow = ep + (size_t)bt * DD;
        const float* dprow = dp + (size_t)(b * UU + u0 + row) * DD;
        #pragma unroll
        for (int c = 0; c < 4; ++c) {
            const int ktag = kq + c * 16;
            const int k0 = ktag * 8;
            float4 e0 = *reinterpret_cast<const float4*>(eprow + k0);
            float4 e1 = *reinterpret_cast<const float4*>(eprow + k0 + 4);
            float4 d0 = *reinterpret_cast<const float4*>(dprow + k0);
            float4 d1 = *reinterpret_cast<const float4*>(dprow + k0 + 4);
            float h0 = tanh_fast(e0.x + d0.x), h1 = tanh_fast(e0.y + d0.y);
            float h2 = tanh_fast(e0.z + d0.z), h3 = tanh_fast(e0.w + d0.w);
            float h4 = tanh_fast(e1.x + d1.x), h5 = tanh_fast(e1.y + d1.y);
            float h6 = tanh_fast(e1.z + d1.z), h7 = tanh_fast(e1.w + d1.w);
            uint4 pk;
            pk.x = (unsigned)f2bf(h0) | ((unsigned)f2bf(h1) << 16);
            pk.y = (unsigned)f2bf(h2) | ((unsigned)f2bf(h3) << 16);
            pk.z = (unsigned)f2bf(h4) | ((unsigned)f2bf(h5) << 16);
            pk.w = (unsigned)f2bf(h6) | ((unsigned)f2bf(h7) << 16);
            const int rsw = ((row ^ ktag) & 31) | (row & 32);
            *reinterpret_cast<uint4*>(ldsA + ktag * 1024 + rsw * 16) = pk;
        }
    }
    __syncthreads();

    const int lane = tid & 63;
    const int w    = tid >> 6;            // 0..15
    const int g    = lane >> 5;
    const int l31  = lane & 31;
    const int ur   = w >> 3;              // u-half
    const int wc   = w & 7;               // 128-col slice

    const unsigned char* hidbase = ldsA + ur * 512;
    const unsigned short* wpbase = w2p + (size_t)(g * 1024 + wc * 128 + l31) * 8;

    f32x16 acc0 = {}, acc1 = {}, acc2 = {}, acc3 = {};

    #define LDH(kk) (*reinterpret_cast<const bf16x8*>(hidbase \
        + ((((kk) & 31) * 2 + g) * 1024) \
        + ((l31 ^ (((((kk) & 31) * 2 + g)) & 31)) << 4)))
    #define LDW(kk, t) (*reinterpret_cast<const bf16x8*>(wpbase \
        + ((size_t)((kk) & 31) * 16384) + (t) * 256))

    bf16x8 wv0 = LDW(0, 0), wv1 = LDW(0, 1), wv2 = LDW(0, 2), wv3 = LDW(0, 3);

    #pragma unroll 2
    for (int kk = 0; kk < 32; ++kk) {
        bf16x8 hf = LDH(kk);
        bf16x8 n0 = LDW(kk + 1, 0), n1 = LDW(kk + 1, 1);
        bf16x8 n2 = LDW(kk + 1, 2), n3 = LDW(kk + 1, 3);
        acc0 = __builtin_amdgcn_mfma_f32_32x32x16_bf16(wv0, hf, acc0, 0, 0, 0);
        acc1 = __builtin_amdgcn_mfma_f32_32x32x16_bf16(wv1, hf, acc1, 0, 0, 0);
        acc2 = __builtin_amdgcn_mfma_f32_32x32x16_bf16(wv2, hf, acc2, 0, 0, 0);
        acc3 = __builtin_amdgcn_mfma_f32_32x32x16_bf16(wv3, hf, acc3, 0, 0, 0);
        wv0 = n0; wv1 = n1; wv2 = n2; wv3 = n3;
    }
    #undef LDH
    #undef LDW

    // ---- row stats: lane-local (each lane holds 64 logits of row ur*32+l31) ----
    const int row = ur * 32 + l31;
    float rmloc = -3.0e38f;
    #pragma unroll
    for (int r = 0; r < 16; ++r)
        rmloc = fmaxf(rmloc, fmaxf(fmaxf(acc0[r], acc1[r]), fmaxf(acc2[r], acc3[r])));
    rmloc = fmaxf(rmloc, __shfl_xor(rmloc, 32, 64));
    if (lane < 32) maxw[row][wc] = rmloc;
    __syncthreads();
    float rmax = maxw[row][0];
    #pragma unroll
    for (int j = 1; j < 8; ++j) rmax = fmaxf(rmax, maxw[row][j]);
    float s = 0.f;
    #pragma unroll
    for (int r = 0; r < 16; ++r)
        s += __expf(acc0[r] - rmax) + __expf(acc1[r] - rmax)
           + __expf(acc2[r] - rmax) + __expf(acc3[r] - rmax);
    s += __shfl_xor(s, 32, 64);
    if (lane < 32) sumw[row][wc] = s;
    __syncthreads();   // also: all hidden reads done -> ldsA reusable as scratch
    float tot = 0.f;
    #pragma unroll
    for (int j = 0; j < 8; ++j) tot += sumw[row][j];
    const float lse = rmax + __logf(tot);
    const float lse_r = __shfl(lse, lane >> 1, 64);  // lse for row ur*32+(lane>>1)

    // ---- transpose through per-wave 4KB LDS slot, then coalesced stores ----
    unsigned char* slot = ldsA + w * 4096;
    const int rr = lane >> 1, seg = lane & 1;
    float* outbase = out + ((size_t)(bt * UU + u0 + ur * 32)) * CC + wc * 128;

    #define CHUNK(T, ACC) { \
        _Pragma("unroll") \
        for (int j = 0; j < 4; ++j) { \
            float4 v; \
            v.x = ACC[4 * j]; v.y = ACC[4 * j + 1]; \
            v.z = ACC[4 * j + 2]; v.w = ACC[4 * j + 3]; \
            const int cg = 2 * j + g; \
            *reinterpret_cast<float4*>(slot + l31 * 128 + ((cg ^ (l31 & 7)) << 4)) = v; \
        } \
        asm volatile("s_waitcnt lgkmcnt(0)" ::: "memory"); \
        float4 q0 = *reinterpret_cast<const float4*>(slot + rr * 128 + (((seg * 4 + 0) ^ (rr & 7)) << 4)); \
        float4 q1 = *reinterpret_cast<const float4*>(slot + rr * 128 + (((seg * 4 + 1) ^ (rr & 7)) << 4)); \
        float4 q2 = *reinterpret_cast<const float4*>(slot + rr * 128 + (((seg * 4 + 2) ^ (rr & 7)) << 4)); \
        float4 q3 = *reinterpret_cast<const float4*>(slot + rr * 128 + (((seg * 4 + 3) ^ (rr & 7)) << 4)); \
        float* op = outbase + (size_t)rr * CC + (T) * 32 + seg * 16; \
        q0.x -= lse_r; q0.y -= lse_r; q0.z -= lse_r; q0.w -= lse_r; \
        q1.x -= lse_r; q1.y -= lse_r; q1.z -= lse_r; q1.w -= lse_r; \
        q2.x -= lse_r; q2.y -= lse_r; q2.z -= lse_r; q2.w -= lse_r; \
        q3.x -= lse_r; q3.y -= lse_r; q3.z -= lse_r; q3.w -= lse_r; \
        *reinterpret_cast<float4*>(op + 0)  = q0; \
        *reinterpret_cast<float4*>(op + 4)  = q1; \
        *reinterpret_cast<float4*>(op + 8)  = q2; \
        *reinterpret_cast<float4*>(op + 12) = q3; \
        asm volatile("s_waitcnt lgkmcnt(0)" ::: "memory"); \
    }
    CHUNK(0, acc0)
    CHUNK(1, acc1)
    CHUNK(2, acc2)
    CHUNK(3, acc3)
    #undef CHUNK
}

extern "C" void kernel_launch(void* const* d_in, const int* in_sizes, int n_in,
                              void* d_out, int out_size, void* d_ws, size_t ws_size,
                              hipStream_t stream) {
    const float* enc = (const float*)d_in[0];   // (B,T,D)
    const float* dec = (const float*)d_in[1];   // (B,U,D)
    const float* W_e = (const float*)d_in[2];   // (D,D)
    const float* W_d = (const float*)d_in[3];   // (D,D)
    const float* b1  = (const float*)d_in[4];   // (D,)
    const float* W2  = (const float*)d_in[5];   // (D,NCLS)
    float* out = (float*)d_out;

    char* ws = (char*)d_ws;                     // needs 4 MB
    float* ep = (float*)(ws);                   // (B*T, D) fp32
    float* dp = (float*)(ws + (2u << 20));      // (B*U, D) fp32
    unsigned short* w2p = (unsigned short*)(ws + (3u << 20)); // packed bf16

    hipLaunchKernelGGL(pack_w2, dim3((DD * CC) / 256), dim3(256), 0, stream, W2, w2p);
    hipLaunchKernelGGL(proj_fused, dim3((BB * TT + BB * UU) / 32, DD / 64), dim3(256), 0,
                       stream, enc, dec, W_e, W_d, b1, ep, dp);
    hipLaunchKernelGGL(joint_kernel, dim3(BB * TT * 2), dim3(1024), 0, stream,
                       ep, dp, w2p, out);
}